// Round 6
// baseline (246.687 us; speedup 1.0000x reference)
//
#include <hip/hip_runtime.h>
#include <hip/hip_bf16.h>
#include <math.h>

#define B_ 2
#define T_ 2048
#define D_ 1024
#define H_ 16
#define QSCALE (0.03125f * 1.44269504088896f)  // 1/sqrt(1024) * log2(e)

typedef _Float16 f16;
using f16x4 = __attribute__((ext_vector_type(4))) _Float16;
using f16x8 = __attribute__((ext_vector_type(8))) _Float16;
using f32x4 = __attribute__((ext_vector_type(4))) float;

__device__ __forceinline__ void gl16(const void* g, void* l) {
  __builtin_amdgcn_global_load_lds(
      (__attribute__((address_space(1))) void*)g,
      (__attribute__((address_space(3))) void*)l, 16, 0, 0);
}

// ---------------------------------------------------------------------------
// prep: cvt_w transpose (blocks 0..1023) + pack_bias (1024..1039) +
// mask scan -> idx/inv/nk + khc pad-row zeroing (1040..1041)
// ---------------------------------------------------------------------------
__global__ __launch_bounds__(256) void prep(
    const int* __restrict__ mask,
    const float* __restrict__ Wq, const float* __restrict__ Wk,
    const float* __restrict__ Wv, const float* __restrict__ Wo,
    const float* __restrict__ bq, const float* __restrict__ bk,
    const float* __restrict__ bv, const float* __restrict__ bo,
    f16* __restrict__ Wt, float* __restrict__ bias,
    int* __restrict__ idx, int* __restrict__ inv, int* __restrict__ nk,
    f16* __restrict__ khc) {
  __shared__ float sh[64][65];
  const int bid = blockIdx.x;
  const int tid = threadIdx.x;

  if (bid < 1024) {  // ---- cvt_w: W[K][N] fp32 -> Wt[N][K] f16 ----
    const int z = bid >> 8;
    const int k0 = ((bid >> 4) & 15) * 64, n0 = (bid & 15) * 64;
    const float* W = (z == 0) ? Wq : (z == 1) ? Wk : (z == 2) ? Wv : Wo;
    const int r = tid >> 2, c0 = (tid & 3) * 16;
#pragma unroll
    for (int i = 0; i < 4; ++i)
      *(float4*)&sh[r][c0 + 4 * i] =
          *(const float4*)&W[(size_t)(k0 + r) * 1024 + n0 + c0 + 4 * i];
    __syncthreads();
    f16 tmp[16];
#pragma unroll
    for (int i = 0; i < 16; ++i) tmp[i] = (f16)sh[c0 + i][r];
    f16* dst = Wt + (size_t)z * 1048576 + (size_t)(n0 + r) * 1024 + k0 + c0;
    *(f16x8*)dst = *(f16x8*)&tmp[0];
    *(f16x8*)(dst + 8) = *(f16x8*)&tmp[8];
  } else if (bid < 1040) {  // ---- pack_bias ----
    const int i = (bid - 1024) * 256 + tid;
    const int z = i >> 10;
    const float* s = (z == 0) ? bq : (z == 1) ? bk : (z == 2) ? bv : bo;
    bias[i] = s[i & 1023];
  } else {  // ---- mask scan + inverse map + khc pad zero, one block/batch ----
    const int b = bid - 1040;
    int* cnt = (int*)sh;
    int loc[8];
    int c = 0;
#pragma unroll
    for (int i = 0; i < 8; ++i) {
      loc[i] = mask[b * T_ + tid * 8 + i];
      c += loc[i];
    }
    cnt[tid] = c;
    __syncthreads();
    for (int off = 1; off < 256; off <<= 1) {
      int vsh = (tid >= off) ? cnt[tid - off] : 0;
      __syncthreads();
      cnt[tid] += vsh;
      __syncthreads();
    }
    int pos = cnt[tid] - c;  // exclusive prefix
#pragma unroll
    for (int i = 0; i < 8; ++i) {
      const int t = tid * 8 + i;
      if (loc[i]) {
        idx[b * T_ + pos] = t;
        inv[b * T_ + t] = pos;
        ++pos;
      } else {
        inv[b * T_ + t] = -1;
      }
    }
    const int n = cnt[255];
    if (tid == 255) nk[b] = n;
    // zero pad rows n..nkt*64-1 of khc (gemm scatter writes only rows < n)
    const int nkt = (n + 63) >> 6;
    const int npadrows = (nkt << 6) - n;
    uint4 z4 = {0u, 0u, 0u, 0u};
    f16* base = khc + ((size_t)b * T_ + n) * D_;
    for (int i = tid; i < npadrows * 128; i += 256)
      *(uint4*)(base + (size_t)i * 8) = z4;
  }
}

// ---------------------------------------------------------------------------
// QKV GEMM with fused fp32->f16 A conversion. C = X @ Wt^T + bias.
// 128x128 tile, BK=32. A: fp32 buffer loads -> cvt -> ds_write (m97 LDS
// addressing, bank-clean); B: gl16 async staging. z in {0,1,2} -> q/k/v.
// z==0: scale epilogue by QSCALE; z==1: scatter rows through inv (compacted
// khc); z==2: plain vh.
// ---------------------------------------------------------------------------
__global__ __launch_bounds__(256) void gemm_qkv(
    const float* __restrict__ xq, const float* __restrict__ xk,
    const float* __restrict__ xv, const f16* __restrict__ Wtb,
    const float* __restrict__ biasb, f16* __restrict__ qh,
    f16* __restrict__ khc, f16* __restrict__ vh,
    const int* __restrict__ inv) {
  __shared__ __align__(16) f16 As[128 * 32];
  __shared__ __align__(16) f16 Bs[128 * 32];
  const int z = blockIdx.z;
  const float* X = (z == 0) ? xq : (z == 1) ? xk : xv;
  const f16* Wt = Wtb + (size_t)z * 1048576;
  const float* bias = biasb + (size_t)z * 1024;
  f16* C = (z == 0) ? qh : (z == 1) ? khc : vh;

  const int tid = threadIdx.x;
  const int wave = tid >> 6, lane = tid & 63;
  const int quad = lane >> 4, l16 = lane & 15;
  const int wm = wave & 1, wn = wave >> 1;
  const int m0 = blockIdx.y * 128, n0 = blockIdx.x * 128;

  f32x4 acc[4][4] = {};

  const float* asrc = X + (size_t)(m0 + (tid >> 2)) * 1024 + (tid & 3) * 8;
  const f16* bsrc = Wt + (size_t)(n0 + (tid >> 2)) * 1024 + (tid & 3) * 8;
  char* bldst = (char*)Bs + tid * 16;
  f16* aw0 = As + tid * 8;
  f16* aw1 = As + 2048 + tid * 8;

  float ar[16];
  auto loadA = [&](int k0) {
    float4 x0 = *(const float4*)(asrc + k0);
    float4 x1 = *(const float4*)(asrc + k0 + 4);
    float4 x2 = *(const float4*)(asrc + 65536 + k0);      // +64 rows
    float4 x3 = *(const float4*)(asrc + 65536 + k0 + 4);
    ar[0] = x0.x; ar[1] = x0.y; ar[2] = x0.z; ar[3] = x0.w;
    ar[4] = x1.x; ar[5] = x1.y; ar[6] = x1.z; ar[7] = x1.w;
    ar[8] = x2.x; ar[9] = x2.y; ar[10] = x2.z; ar[11] = x2.w;
    ar[12] = x3.x; ar[13] = x3.y; ar[14] = x3.z; ar[15] = x3.w;
  };
  loadA(0);

  for (int kt = 0; kt < 32; ++kt) {
    if (kt) __syncthreads();
    gl16(bsrc, bldst);
    gl16(bsrc + 65536, bldst + 4096);  // +64 rows of Wt
    bsrc += 32;
    f16x8 h0, h1;
#pragma unroll
    for (int i = 0; i < 8; ++i) { h0[i] = (f16)ar[i]; h1[i] = (f16)ar[8 + i]; }
    *(f16x8*)aw0 = h0;
    *(f16x8*)aw1 = h1;
    __syncthreads();
    if (kt + 1 < 32) loadA(32 * (kt + 1));  // overlap next A fetch with MFMA

    f16x8 af[4], bf[4];
#pragma unroll
    for (int t = 0; t < 4; ++t)
      af[t] = *(const f16x8*)&As[(64 * wm + 16 * t + l16) * 32 + quad * 8];
#pragma unroll
    for (int t = 0; t < 4; ++t)
      bf[t] = *(const f16x8*)&Bs[(64 * wn + 16 * t + l16) * 32 + quad * 8];
#pragma unroll
    for (int i = 0; i < 4; ++i)
#pragma unroll
      for (int j = 0; j < 4; ++j)
        acc[i][j] = __builtin_amdgcn_mfma_f32_16x16x32_f16(af[i], bf[j], acc[i][j], 0, 0, 0);
  }

  const int cm = m0 + 64 * wm + 4 * quad;
  const int cn = n0 + 64 * wn + l16;
  float bv[4];
#pragma unroll
  for (int tn = 0; tn < 4; ++tn) bv[tn] = bias[cn + 16 * tn];

  if (z == 1) {  // K-compaction scatter
    const int bb = m0 >> 11;
#pragma unroll
    for (int tm = 0; tm < 4; ++tm) {
#pragma unroll
      for (int r = 0; r < 4; ++r) {
        const int m = cm + 16 * tm + r;
        const int j = inv[m];
        if (j >= 0) {
          f16* row = C + ((size_t)(bb << 11) + j) * 1024;
#pragma unroll
          for (int tn = 0; tn < 4; ++tn)
            row[cn + 16 * tn] = (f16)(acc[tm][tn][r] + bv[tn]);
        }
      }
    }
  } else {
    const float scl = (z == 0) ? QSCALE : 1.f;
#pragma unroll
    for (int tm = 0; tm < 4; ++tm)
#pragma unroll
      for (int r = 0; r < 4; ++r) {
        f16* row = C + (size_t)(cm + 16 * tm + r) * 1024;
#pragma unroll
        for (int tn = 0; tn < 4; ++tn)
          row[cn + 16 * tn] = (f16)((acc[tm][tn][r] + bv[tn]) * scl);
      }
  }
}

// ---------------------------------------------------------------------------
// vtrans: gather + transpose V. vhT[bh][dh][j] = vh[b][idx[j]][h*64+dh]
// ---------------------------------------------------------------------------
__global__ __launch_bounds__(256) void vtrans(
    const f16* __restrict__ vh, const int* __restrict__ idx,
    const int* __restrict__ nk, f16* __restrict__ vhT) {
  const int tt = blockIdx.x, bh = blockIdx.y;
  const int b = bh >> 4, h = bh & 15;
  const int n = nk[b];
  const int nkt = (n + 63) >> 6;
  if (tt >= nkt) return;
  __shared__ f16 t[64][72];
  const int tid = threadIdx.x;
  const int r = tid >> 2, cq = 16 * (tid & 3);

  const int j = tt * 64 + r;
  uint4 v0 = {0u, 0u, 0u, 0u}, v1 = {0u, 0u, 0u, 0u};
  if (j < n) {
    const int tsrc = idx[b * T_ + j];
    const uint4* src = (const uint4*)(vh + ((size_t)b * T_ + tsrc) * D_ + h * 64 + cq);
    v0 = src[0]; v1 = src[1];
  }
  *(uint4*)&t[r][cq]     = v0;
  *(uint4*)&t[r][cq + 8] = v1;
  __syncthreads();

  f16 tmp[16];
#pragma unroll
  for (int xx = 0; xx < 16; ++xx) {
    int x = (xx + r) & 15;
    tmp[x] = t[cq + x][r];
  }
  f16* dst = vhT + ((size_t)bh * 64 + r) * T_ + tt * 64 + cq;
  *(uint4*)&dst[0] = *(uint4*)&tmp[0];
  *(uint4*)&dst[8] = *(uint4*)&tmp[8];
}

// ---------------------------------------------------------------------------
// Split-K flash attention over compacted keys. Grid (16, 32, 2): block
// (qt, bh, ks) handles half the key tiles; writes RAW O partial (f16) and
// l partial (fp32). Fixed-max softmax -> merge is (Oa+Ob)/(la+lb), done in
// gemm_out staging. Wave owns 32 q-rows (2 l16-groups); Q direct from global.
// qh pre-scaled by SCALE*log2e -> P = exp2(S); pad keys give p=1, subtracted
// by the block owning the last tile.
// ---------------------------------------------------------------------------
__global__ __launch_bounds__(256) void attn_mfma(
    const f16* __restrict__ qh, const f16* __restrict__ khc,
    const f16* __restrict__ vhT, const int* __restrict__ nkd,
    f16* __restrict__ opart, float* __restrict__ lpart) {
  __shared__ f16 Ks[64][72];     // [key][dh]
  __shared__ f16 Vt[64][72];     // [dh][key]
  __shared__ f16 Ps[4][32][72];  // per-wave [qrow][key]

  const int qt = blockIdx.x, bh = blockIdx.y, ks = blockIdx.z;
  const int b = bh >> 4, h = bh & 15;
  const int tid = threadIdx.x;
  const int wave = tid >> 6, lane = tid & 63;
  const int quad = lane >> 4, l16 = lane & 15;
  const int sr = tid >> 2, sq = 16 * (tid & 3);

  const int n = nkd[b];
  const int nkt = (n + 63) >> 6;
  const int hn = (nkt + 1) >> 1;
  const int t_begin = ks ? hn : 0;
  const int t_end = ks ? nkt : hn;
  const bool owns_last = (t_end == nkt) && (t_end > t_begin);
  const int npad = (nkt << 6) - n;

  // Q fragments direct from global: rows qt*128 + wave*32 + 16*gq + l16
  f16x8 qf[2][2];
#pragma unroll
  for (int gq = 0; gq < 2; ++gq) {
    const f16* qp = qh + ((size_t)(b * T_ + qt * 128 + wave * 32 + 16 * gq + l16)) * D_ + h * 64 + quad * 8;
    qf[gq][0] = *(const f16x8*)qp;
    qf[gq][1] = *(const f16x8*)(qp + 32);
  }

  float lsum[2] = {0.f, 0.f};
  f32x4 o[2][4] = {};

  const f16* kbase = khc + (size_t)b * T_ * D_ + h * 64;
  const f16* vbase = vhT + ((size_t)bh * 64 + sr) * T_;

  uint4 kr0, kr1, vr0, vr1;
  auto load_kv = [&](int kt) {
    const uint4* kp = (const uint4*)(kbase + (size_t)(kt * 64 + sr) * D_ + sq);
    kr0 = kp[0]; kr1 = kp[1];
    const uint4* vp = (const uint4*)(vbase + kt * 64 + sq);
    vr0 = vp[0]; vr1 = vp[1];
  };
  if (t_begin < t_end) load_kv(t_begin);

  for (int kt = t_begin; kt < t_end; ++kt) {
    *(uint4*)&Ks[sr][sq]     = kr0;
    *(uint4*)&Ks[sr][sq + 8] = kr1;
    *(uint4*)&Vt[sr][sq]     = vr0;
    *(uint4*)&Vt[sr][sq + 8] = vr1;
    __syncthreads();
    if (kt + 1 < t_end) load_kv(kt + 1);  // prefetch next tile into regs

    // ---- S^T = K Q^T, K frags shared across q-groups ----
#pragma unroll
    for (int tn = 0; tn < 4; ++tn) {
      f16x8 kf0 = *(const f16x8*)&Ks[16 * tn + l16][quad * 8];
      f16x8 kf1 = *(const f16x8*)&Ks[16 * tn + l16][32 + quad * 8];
#pragma unroll
      for (int gq = 0; gq < 2; ++gq) {
        f32x4 s = {0.f, 0.f, 0.f, 0.f};
        s = __builtin_amdgcn_mfma_f32_16x16x32_f16(kf0, qf[gq][0], s, 0, 0, 0);
        s = __builtin_amdgcn_mfma_f32_16x16x32_f16(kf1, qf[gq][1], s, 0, 0, 0);
        float p0 = exp2f(s[0]), p1 = exp2f(s[1]);
        float p2 = exp2f(s[2]), p3 = exp2f(s[3]);
        lsum[gq] += (p0 + p1) + (p2 + p3);
        f16x4 pk;
        pk[0] = (f16)p0; pk[1] = (f16)p1; pk[2] = (f16)p2; pk[3] = (f16)p3;
        *(f16x4*)&Ps[wave][16 * gq + l16][16 * tn + 4 * quad] = pk;
      }
    }

    // ---- O += P V, V frags shared across q-groups ----
    f16x8 pf[2][2];
#pragma unroll
    for (int gq = 0; gq < 2; ++gq) {
      pf[gq][0] = *(const f16x8*)&Ps[wave][16 * gq + l16][quad * 8];
      pf[gq][1] = *(const f16x8*)&Ps[wave][16 * gq + l16][32 + quad * 8];
    }
#pragma unroll
    for (int t = 0; t < 4; ++t) {
      f16x8 vf0 = *(const f16x8*)&Vt[16 * t + l16][quad * 8];
      f16x8 vf1 = *(const f16x8*)&Vt[16 * t + l16][32 + quad * 8];
#pragma unroll
      for (int gq = 0; gq < 2; ++gq) {
        o[gq][t] = __builtin_amdgcn_mfma_f32_16x16x32_f16(pf[gq][0], vf0, o[gq][t], 0, 0, 0);
        o[gq][t] = __builtin_amdgcn_mfma_f32_16x16x32_f16(pf[gq][1], vf1, o[gq][t], 0, 0, 0);
      }
    }
    __syncthreads();
  }

  f16* obase = opart + (size_t)ks * 4194304;
  float* lbase = lpart + (size_t)ks * 65536 + (size_t)bh * 2048;
#pragma unroll
  for (int gq = 0; gq < 2; ++gq) {
    float ls = lsum[gq];
    ls += __shfl_xor(ls, 16);   // quads hold disjoint key subsets
    ls += __shfl_xor(ls, 32);
    if (owns_last) ls -= (float)npad;
    const int qrow0 = qt * 128 + wave * 32 + 16 * gq;
    if (quad == 0) lbase[qrow0 + l16] = ls;  // per-qrow l partial
    const size_t orow = (size_t)(b * T_ + qrow0 + 4 * quad);
#pragma unroll
    for (int r = 0; r < 4; ++r)
#pragma unroll
      for (int t = 0; t < 4; ++t)
        obase[(orow + r) * D_ + h * 64 + 16 * t + l16] = (f16)o[gq][t][r];
  }
}

// ---------------------------------------------------------------------------
// Output GEMM with fused split-K merge in A-staging:
// A row = ((Oa+Ob) / (la+lb)) converted to f16. C = A @ Wo^T + bo (fp32 out).
// TM=64 x 128 tile, BK=32, B via gl16.
// ---------------------------------------------------------------------------
__global__ __launch_bounds__(256) void gemm_out(
    const f16* __restrict__ opart, const float* __restrict__ lpart,
    const f16* __restrict__ Wt3, const float* __restrict__ bias3,
    float* __restrict__ out) {
  __shared__ __align__(16) f16 As[64 * 32];
  __shared__ __align__(16) f16 Bs[128 * 32];
  const int tid = threadIdx.x;
  const int wave = tid >> 6, lane = tid & 63;
  const int quad = lane >> 4, l16 = lane & 15;
  const int wm = wave & 1, wn = wave >> 1;
  const int m0 = blockIdx.y * 64, n0 = blockIdx.x * 128;

  f32x4 acc[2][4] = {};

  const int row = m0 + (tid >> 2);
  const int cq = (tid & 3) * 8;
  const f16* oa = opart + (size_t)row * 1024 + cq;
  const f16* ob = oa + 4194304;
  const float* lp = lpart + (size_t)(row >> 11) * 32768 + (row & 2047);
  const f16* bsrc = Wt3 + (size_t)(n0 + (tid >> 2)) * 1024 + cq;
  char* bldst = (char*)Bs + tid * 16;

  for (int kt = 0; kt < 32; ++kt) {
    if (kt) __syncthreads();
    gl16(bsrc, bldst);
    gl16(bsrc + 65536, bldst + 4096);
    bsrc += 32;
    // fused split-K merge for this thread's 8 A elements
    const int h = (kt * 32 + cq) >> 6;
    const float la = lp[h * 2048];
    const float lb = lp[65536 + h * 2048];
    const float invl = 1.f / (la + lb);
    f16x8 a8 = *(const f16x8*)(oa + kt * 32);
    f16x8 b8 = *(const f16x8*)(ob + kt * 32);
    f16x8 hv;
#pragma unroll
    for (int i = 0; i < 8; ++i)
      hv[i] = (f16)(((float)a8[i] + (float)b8[i]) * invl);
    *(f16x8*)(As + tid * 8) = hv;
    __syncthreads();

    f16x8 af[2], bf[4];
#pragma unroll
    for (int t = 0; t < 2; ++t)
      af[t] = *(const f16x8*)&As[(32 * wm + 16 * t + l16) * 32 + quad * 8];
#pragma unroll
    for (int t = 0; t < 4; ++t)
      bf[t] = *(const f16x8*)&Bs[(64 * wn + 16 * t + l16) * 32 + quad * 8];
#pragma unroll
    for (int i = 0; i < 2; ++i)
#pragma unroll
      for (int j = 0; j < 4; ++j)
        acc[i][j] = __builtin_amdgcn_mfma_f32_16x16x32_f16(af[i], bf[j], acc[i][j], 0, 0, 0);
  }

  const int cm = m0 + 32 * wm + 4 * quad;
  const int cn = n0 + 64 * wn + l16;
#pragma unroll
  for (int tn = 0; tn < 4; ++tn) {
    const float bv = bias3[cn + 16 * tn];
#pragma unroll
    for (int tm = 0; tm < 2; ++tm)
#pragma unroll
      for (int r = 0; r < 4; ++r)
        out[(size_t)(cm + 16 * tm + r) * 1024 + cn + 16 * tn] = acc[tm][tn][r] + bv;
  }
}

// ---------------------------------------------------------------------------
extern "C" void kernel_launch(void* const* d_in, const int* in_sizes, int n_in,
                              void* d_out, int out_size, void* d_ws, size_t ws_size,
                              hipStream_t stream) {
  const float* q  = (const float*)d_in[0];
  const float* k  = (const float*)d_in[1];
  const float* v  = (const float*)d_in[2];
  const int* mask = (const int*)d_in[3];
  const float* Wq = (const float*)d_in[4];
  const float* bq = (const float*)d_in[5];
  const float* Wk = (const float*)d_in[6];
  const float* bk = (const float*)d_in[7];
  const float* Wv = (const float*)d_in[8];
  const float* bv = (const float*)d_in[9];
  const float* Wo = (const float*)d_in[10];
  const float* bo = (const float*)d_in[11];
  float* out = (float*)d_out;

  // ws layout (bytes):
  //  0         qh    (8 MB)
  //  8388608   vh    (8 MB)
  //  16777216  khc   (8 MB)
  //  25165824  vhT   (8 MB)
  //  33554432  opart (16 MB: 2 x 8 MB)
  //  50331648  Wt    (8 MB: 4 x 2 MB)
  //  58720256  lpart (512 KB: 2 x 64 K floats)
  //  59244544  bias (16 KB) | idx (16 KB) | inv (16 KB) | nk (8 B)
  char* ws = (char*)d_ws;
  f16* qh     = (f16*)(ws);
  f16* vh     = (f16*)(ws + 8388608);
  f16* khc    = (f16*)(ws + 16777216);
  f16* vhT    = (f16*)(ws + 25165824);
  f16* opart  = (f16*)(ws + 33554432);
  f16* Wt     = (f16*)(ws + 50331648);
  float* lpart = (float*)(ws + 58720256);
  float* bsw  = (float*)(ws + 59244544);
  int* idx    = (int*)(ws + 59260928);
  int* inv    = (int*)(ws + 59277312);
  int* nk     = (int*)(ws + 59293696);

  dim3 blk(256);

  prep<<<dim3(1042), blk, 0, stream>>>(mask, Wq, Wk, Wv, Wo, bq, bk, bv, bo,
                                       Wt, bsw, idx, inv, nk, khc);

  gemm_qkv<<<dim3(8, 32, 3), blk, 0, stream>>>(q, k, v, Wt, bsw,
                                               qh, khc, vh, inv);

  vtrans<<<dim3(32, 32), blk, 0, stream>>>(vh, idx, nk, vhT);

  attn_mfma<<<dim3(16, 32, 2), blk, 0, stream>>>(qh, khc, vhT, nk,
                                                 opart, lpart);

  gemm_out<<<dim3(8, 64), blk, 0, stream>>>(opart, lpart, Wt + 3145728,
                                            bsw + 3072, out);
}

// Round 7
// 230.416 us; speedup vs baseline: 1.0706x; 1.0706x over previous
//
#include <hip/hip_runtime.h>
#include <hip/hip_bf16.h>
#include <math.h>

#define B_ 2
#define T_ 2048
#define D_ 1024
#define H_ 16
#define QSCALE (0.03125f * 1.44269504088896f)  // 1/sqrt(1024) * log2(e)

typedef _Float16 f16;
using f16x4 = __attribute__((ext_vector_type(4))) _Float16;
using f16x8 = __attribute__((ext_vector_type(8))) _Float16;
using f32x4 = __attribute__((ext_vector_type(4))) float;

__device__ __forceinline__ void gl16(const void* g, void* l) {
  __builtin_amdgcn_global_load_lds(
      (__attribute__((address_space(1))) void*)g,
      (__attribute__((address_space(3))) void*)l, 16, 0, 0);
}

// ---------------------------------------------------------------------------
// prep: cvt_x (0..6143) + cvt_w transpose (6144..7167) + pack_bias
// (7168..7183) + mask scan -> idx/inv/nk + khc pad-row zeroing (7184..7185)
// ---------------------------------------------------------------------------
__global__ __launch_bounds__(256) void prep(
    const float* __restrict__ q, const float* __restrict__ k,
    const float* __restrict__ v, const int* __restrict__ mask,
    const float* __restrict__ Wq, const float* __restrict__ Wk,
    const float* __restrict__ Wv, const float* __restrict__ Wo,
    const float* __restrict__ bq, const float* __restrict__ bk,
    const float* __restrict__ bv, const float* __restrict__ bo,
    f16* __restrict__ xqkv, f16* __restrict__ Wt, float* __restrict__ bias,
    int* __restrict__ idx, int* __restrict__ inv, int* __restrict__ nk,
    f16* __restrict__ khc) {
  __shared__ float sh[64][65];
  const int bid = blockIdx.x;
  const int tid = threadIdx.x;

  if (bid < 6144) {  // ---- cvt_x: fp32 -> f16 ----
    const int z = bid / 2048;
    const float* src = (z == 0) ? q : (z == 1) ? k : v;
    const size_t i = ((size_t)(bid % 2048) * 256 + tid) * 8;
    float4 a = *(const float4*)(src + i);
    float4 b = *(const float4*)(src + i + 4);
    f16x8 o;
    o[0] = (f16)a.x; o[1] = (f16)a.y; o[2] = (f16)a.z; o[3] = (f16)a.w;
    o[4] = (f16)b.x; o[5] = (f16)b.y; o[6] = (f16)b.z; o[7] = (f16)b.w;
    *(f16x8*)(xqkv + (size_t)z * 4194304 + i) = o;
  } else if (bid < 7168) {  // ---- cvt_w: W[K][N] fp32 -> Wt[N][K] f16 ----
    const int id = bid - 6144;
    const int z = id >> 8;
    const int k0 = ((id >> 4) & 15) * 64, n0 = (id & 15) * 64;
    const float* W = (z == 0) ? Wq : (z == 1) ? Wk : (z == 2) ? Wv : Wo;
    const int r = tid >> 2, c0 = (tid & 3) * 16;
#pragma unroll
    for (int i = 0; i < 4; ++i)
      *(float4*)&sh[r][c0 + 4 * i] =
          *(const float4*)&W[(size_t)(k0 + r) * 1024 + n0 + c0 + 4 * i];
    __syncthreads();
    f16 tmp[16];
#pragma unroll
    for (int i = 0; i < 16; ++i) tmp[i] = (f16)sh[c0 + i][r];
    f16* dst = Wt + (size_t)z * 1048576 + (size_t)(n0 + r) * 1024 + k0 + c0;
    *(f16x8*)dst = *(f16x8*)&tmp[0];
    *(f16x8*)(dst + 8) = *(f16x8*)&tmp[8];
  } else if (bid < 7184) {  // ---- pack_bias ----
    const int i = (bid - 7168) * 256 + tid;
    const int z = i >> 10;
    const float* s = (z == 0) ? bq : (z == 1) ? bk : (z == 2) ? bv : bo;
    bias[i] = s[i & 1023];
  } else {  // ---- mask scan + inverse map + khc pad zero, one block/batch ----
    const int b = bid - 7184;
    int* cnt = (int*)sh;
    int loc[8];
    int c = 0;
#pragma unroll
    for (int i = 0; i < 8; ++i) {
      loc[i] = mask[b * T_ + tid * 8 + i];
      c += loc[i];
    }
    cnt[tid] = c;
    __syncthreads();
    for (int off = 1; off < 256; off <<= 1) {
      int vsh = (tid >= off) ? cnt[tid - off] : 0;
      __syncthreads();
      cnt[tid] += vsh;
      __syncthreads();
    }
    int pos = cnt[tid] - c;  // exclusive prefix
#pragma unroll
    for (int i = 0; i < 8; ++i) {
      const int t = tid * 8 + i;
      if (loc[i]) {
        idx[b * T_ + pos] = t;
        inv[b * T_ + t] = pos;
        ++pos;
      } else {
        inv[b * T_ + t] = -1;
      }
    }
    const int n = cnt[255];
    if (tid == 255) nk[b] = n;
    // zero pad rows n..nkt*64-1 of khc (gemm scatter writes only rows < n)
    const int nkt = (n + 63) >> 6;
    const int npadrows = (nkt << 6) - n;
    uint4 z4 = {0u, 0u, 0u, 0u};
    f16* base = khc + ((size_t)b * T_ + n) * D_;
    for (int i = tid; i < npadrows * 128; i += 256)
      *(uint4*)(base + (size_t)i * 8) = z4;
  }
}

// ---------------------------------------------------------------------------
// m97-style QKV GEMM: C = X @ Wt^T + bias, f16 in (X pre-converted).
// 128x128 tile, BK=32, all-gl16 async staging (the R5 config that ran
// 43.9 us; R6's fused fp32 conversion regressed to 71 us — reverted).
// z in {0,1,2}: q (scaled by QSCALE) / k (scatter through inv into khc) / v.
// ---------------------------------------------------------------------------
__global__ __launch_bounds__(256) void gemm_qkv(
    const f16* __restrict__ Xb, const f16* __restrict__ Wtb,
    const float* __restrict__ biasb, f16* __restrict__ qh,
    f16* __restrict__ khc, f16* __restrict__ vh,
    const int* __restrict__ inv) {
  __shared__ __align__(16) f16 As[128 * 32];
  __shared__ __align__(16) f16 Bs[128 * 32];
  const int z = blockIdx.z;
  const f16* X = Xb + (size_t)z * 4194304;
  const f16* Wt = Wtb + (size_t)z * 1048576;
  const float* bias = biasb + (size_t)z * 1024;
  f16* C = (z == 0) ? qh : (z == 1) ? khc : vh;

  const int tid = threadIdx.x;
  const int wave = tid >> 6, lane = tid & 63;
  const int quad = lane >> 4, l16 = lane & 15;
  const int wm = wave & 1, wn = wave >> 1;
  const int m0 = blockIdx.y * 128, n0 = blockIdx.x * 128;

  f32x4 acc[4][4] = {};

  const f16* asrc = X + (size_t)(m0 + (tid >> 2)) * 1024 + (tid & 3) * 8;
  const f16* bsrc = Wt + (size_t)(n0 + (tid >> 2)) * 1024 + (tid & 3) * 8;
  char* aldst = (char*)As + tid * 16;
  char* bldst = (char*)Bs + tid * 16;

  for (int kt = 0; kt < 32; ++kt) {
    if (kt) __syncthreads();
    gl16(asrc, aldst);
    gl16(asrc + 65536, aldst + 4096);   // +64 rows
    gl16(bsrc, bldst);
    gl16(bsrc + 65536, bldst + 4096);
    asrc += 32; bsrc += 32;
    __syncthreads();

    f16x8 af[4], bf[4];
#pragma unroll
    for (int t = 0; t < 4; ++t)
      af[t] = *(const f16x8*)&As[(64 * wm + 16 * t + l16) * 32 + quad * 8];
#pragma unroll
    for (int t = 0; t < 4; ++t)
      bf[t] = *(const f16x8*)&Bs[(64 * wn + 16 * t + l16) * 32 + quad * 8];
#pragma unroll
    for (int i = 0; i < 4; ++i)
#pragma unroll
      for (int j = 0; j < 4; ++j)
        acc[i][j] = __builtin_amdgcn_mfma_f32_16x16x32_f16(af[i], bf[j], acc[i][j], 0, 0, 0);
  }

  const int cm = m0 + 64 * wm + 4 * quad;
  const int cn = n0 + 64 * wn + l16;
  float bv[4];
#pragma unroll
  for (int tn = 0; tn < 4; ++tn) bv[tn] = bias[cn + 16 * tn];

  if (z == 1) {  // K-compaction scatter
    const int bb = m0 >> 11;
#pragma unroll
    for (int tm = 0; tm < 4; ++tm) {
#pragma unroll
      for (int r = 0; r < 4; ++r) {
        const int m = cm + 16 * tm + r;
        const int j = inv[m];
        if (j >= 0) {
          f16* row = C + ((size_t)(bb << 11) + j) * 1024;
#pragma unroll
          for (int tn = 0; tn < 4; ++tn)
            row[cn + 16 * tn] = (f16)(acc[tm][tn][r] + bv[tn]);
        }
      }
    }
  } else {
    const float scl = (z == 0) ? QSCALE : 1.f;
#pragma unroll
    for (int tm = 0; tm < 4; ++tm)
#pragma unroll
      for (int r = 0; r < 4; ++r) {
        f16* row = C + (size_t)(cm + 16 * tm + r) * 1024;
#pragma unroll
        for (int tn = 0; tn < 4; ++tn)
          row[cn + 16 * tn] = (f16)((acc[tm][tn][r] + bv[tn]) * scl);
      }
  }
}

// ---------------------------------------------------------------------------
// vtrans: gather + transpose V. vhT[bh][dh][j] = vh[b][idx[j]][h*64+dh]
// ---------------------------------------------------------------------------
__global__ __launch_bounds__(256) void vtrans(
    const f16* __restrict__ vh, const int* __restrict__ idx,
    const int* __restrict__ nk, f16* __restrict__ vhT) {
  const int tt = blockIdx.x, bh = blockIdx.y;
  const int b = bh >> 4, h = bh & 15;
  const int n = nk[b];
  const int nkt = (n + 63) >> 6;
  if (tt >= nkt) return;
  __shared__ f16 t[64][72];
  const int tid = threadIdx.x;
  const int r = tid >> 2, cq = 16 * (tid & 3);

  const int j = tt * 64 + r;
  uint4 v0 = {0u, 0u, 0u, 0u}, v1 = {0u, 0u, 0u, 0u};
  if (j < n) {
    const int tsrc = idx[b * T_ + j];
    const uint4* src = (const uint4*)(vh + ((size_t)b * T_ + tsrc) * D_ + h * 64 + cq);
    v0 = src[0]; v1 = src[1];
  }
  *(uint4*)&t[r][cq]     = v0;
  *(uint4*)&t[r][cq + 8] = v1;
  __syncthreads();

  f16 tmp[16];
#pragma unroll
  for (int xx = 0; xx < 16; ++xx) {
    int x = (xx + r) & 15;
    tmp[x] = t[cq + x][r];
  }
  f16* dst = vhT + ((size_t)bh * 64 + r) * T_ + tt * 64 + cq;
  *(uint4*)&dst[0] = *(uint4*)&tmp[0];
  *(uint4*)&dst[8] = *(uint4*)&tmp[8];
}

// ---------------------------------------------------------------------------
// Split-K flash attention over compacted keys. Grid (16, 32, 2): block
// (qt, bh, ks) handles half the key tiles; writes RAW O partial (f16) and
// l partial (fp32). Fixed-max softmax -> merge is (Oa+Ob)/(la+lb), done in
// gemm_out staging. Wave owns 32 q-rows; Q frags direct from global.
// ---------------------------------------------------------------------------
__global__ __launch_bounds__(256) void attn_mfma(
    const f16* __restrict__ qh, const f16* __restrict__ khc,
    const f16* __restrict__ vhT, const int* __restrict__ nkd,
    f16* __restrict__ opart, float* __restrict__ lpart) {
  __shared__ f16 Ks[64][72];     // [key][dh]
  __shared__ f16 Vt[64][72];     // [dh][key]
  __shared__ f16 Ps[4][32][72];  // per-wave [qrow][key]

  const int qt = blockIdx.x, bh = blockIdx.y, ks = blockIdx.z;
  const int b = bh >> 4, h = bh & 15;
  const int tid = threadIdx.x;
  const int wave = tid >> 6, lane = tid & 63;
  const int quad = lane >> 4, l16 = lane & 15;
  const int sr = tid >> 2, sq = 16 * (tid & 3);

  const int n = nkd[b];
  const int nkt = (n + 63) >> 6;
  const int hn = (nkt + 1) >> 1;
  const int t_begin = ks ? hn : 0;
  const int t_end = ks ? nkt : hn;
  const bool owns_last = (t_end == nkt) && (t_end > t_begin);
  const int npad = (nkt << 6) - n;

  f16x8 qf[2][2];
#pragma unroll
  for (int gq = 0; gq < 2; ++gq) {
    const f16* qp = qh + ((size_t)(b * T_ + qt * 128 + wave * 32 + 16 * gq + l16)) * D_ + h * 64 + quad * 8;
    qf[gq][0] = *(const f16x8*)qp;
    qf[gq][1] = *(const f16x8*)(qp + 32);
  }

  float lsum[2] = {0.f, 0.f};
  f32x4 o[2][4] = {};

  const f16* kbase = khc + (size_t)b * T_ * D_ + h * 64;
  const f16* vbase = vhT + ((size_t)bh * 64 + sr) * T_;

  uint4 kr0, kr1, vr0, vr1;
  auto load_kv = [&](int kt) {
    const uint4* kp = (const uint4*)(kbase + (size_t)(kt * 64 + sr) * D_ + sq);
    kr0 = kp[0]; kr1 = kp[1];
    const uint4* vp = (const uint4*)(vbase + kt * 64 + sq);
    vr0 = vp[0]; vr1 = vp[1];
  };
  if (t_begin < t_end) load_kv(t_begin);

  for (int kt = t_begin; kt < t_end; ++kt) {
    *(uint4*)&Ks[sr][sq]     = kr0;
    *(uint4*)&Ks[sr][sq + 8] = kr1;
    *(uint4*)&Vt[sr][sq]     = vr0;
    *(uint4*)&Vt[sr][sq + 8] = vr1;
    __syncthreads();
    if (kt + 1 < t_end) load_kv(kt + 1);  // prefetch next tile into regs

    // ---- S^T = K Q^T, K frags shared across q-groups ----
#pragma unroll
    for (int tn = 0; tn < 4; ++tn) {
      f16x8 kf0 = *(const f16x8*)&Ks[16 * tn + l16][quad * 8];
      f16x8 kf1 = *(const f16x8*)&Ks[16 * tn + l16][32 + quad * 8];
#pragma unroll
      for (int gq = 0; gq < 2; ++gq) {
        f32x4 s = {0.f, 0.f, 0.f, 0.f};
        s = __builtin_amdgcn_mfma_f32_16x16x32_f16(kf0, qf[gq][0], s, 0, 0, 0);
        s = __builtin_amdgcn_mfma_f32_16x16x32_f16(kf1, qf[gq][1], s, 0, 0, 0);
        float p0 = exp2f(s[0]), p1 = exp2f(s[1]);
        float p2 = exp2f(s[2]), p3 = exp2f(s[3]);
        lsum[gq] += (p0 + p1) + (p2 + p3);
        f16x4 pk;
        pk[0] = (f16)p0; pk[1] = (f16)p1; pk[2] = (f16)p2; pk[3] = (f16)p3;
        *(f16x4*)&Ps[wave][16 * gq + l16][16 * tn + 4 * quad] = pk;
      }
    }

    // ---- O += P V, V frags shared across q-groups ----
    f16x8 pf[2][2];
#pragma unroll
    for (int gq = 0; gq < 2; ++gq) {
      pf[gq][0] = *(const f16x8*)&Ps[wave][16 * gq + l16][quad * 8];
      pf[gq][1] = *(const f16x8*)&Ps[wave][16 * gq + l16][32 + quad * 8];
    }
#pragma unroll
    for (int t = 0; t < 4; ++t) {
      f16x8 vf0 = *(const f16x8*)&Vt[16 * t + l16][quad * 8];
      f16x8 vf1 = *(const f16x8*)&Vt[16 * t + l16][32 + quad * 8];
#pragma unroll
      for (int gq = 0; gq < 2; ++gq) {
        o[gq][t] = __builtin_amdgcn_mfma_f32_16x16x32_f16(pf[gq][0], vf0, o[gq][t], 0, 0, 0);
        o[gq][t] = __builtin_amdgcn_mfma_f32_16x16x32_f16(pf[gq][1], vf1, o[gq][t], 0, 0, 0);
      }
    }
    __syncthreads();
  }

  f16* obase = opart + (size_t)ks * 4194304;
  float* lbase = lpart + (size_t)ks * 65536 + (size_t)bh * 2048;
#pragma unroll
  for (int gq = 0; gq < 2; ++gq) {
    float ls = lsum[gq];
    ls += __shfl_xor(ls, 16);   // quads hold disjoint key subsets
    ls += __shfl_xor(ls, 32);
    if (owns_last) ls -= (float)npad;
    const int qrow0 = qt * 128 + wave * 32 + 16 * gq;
    if (quad == 0) lbase[qrow0 + l16] = ls;
    const size_t orow = (size_t)(b * T_ + qrow0 + 4 * quad);
#pragma unroll
    for (int r = 0; r < 4; ++r)
#pragma unroll
      for (int t = 0; t < 4; ++t)
        obase[(orow + r) * D_ + h * 64 + 16 * t + l16] = (f16)o[gq][t][r];
  }
}

// ---------------------------------------------------------------------------
// Output GEMM with fused split-K merge in A-staging:
// A row = ((Oa+Ob) / (la+lb)) as f16. C = A @ Wo^T + bo (fp32 out).
// TM=64 x 128 tile, BK=32, B via gl16.
// ---------------------------------------------------------------------------
__global__ __launch_bounds__(256) void gemm_out(
    const f16* __restrict__ opart, const float* __restrict__ lpart,
    const f16* __restrict__ Wt3, const float* __restrict__ bias3,
    float* __restrict__ out) {
  __shared__ __align__(16) f16 As[64 * 32];
  __shared__ __align__(16) f16 Bs[128 * 32];
  const int tid = threadIdx.x;
  const int wave = tid >> 6, lane = tid & 63;
  const int quad = lane >> 4, l16 = lane & 15;
  const int wm = wave & 1, wn = wave >> 1;
  const int m0 = blockIdx.y * 64, n0 = blockIdx.x * 128;

  f32x4 acc[2][4] = {};

  const int row = m0 + (tid >> 2);
  const int cq = (tid & 3) * 8;
  const f16* oa = opart + (size_t)row * 1024 + cq;
  const f16* ob = oa + 4194304;
  const float* lp = lpart + (size_t)(row >> 11) * 32768 + (row & 2047);
  const f16* bsrc = Wt3 + (size_t)(n0 + (tid >> 2)) * 1024 + cq;
  char* bldst = (char*)Bs + tid * 16;

  for (int kt = 0; kt < 32; ++kt) {
    if (kt) __syncthreads();
    gl16(bsrc, bldst);
    gl16(bsrc + 65536, bldst + 4096);
    bsrc += 32;
    const int h = (kt * 32 + cq) >> 6;
    const float la = lp[h * 2048];
    const float lb = lp[65536 + h * 2048];
    const float invl = 1.f / (la + lb);
    f16x8 a8 = *(const f16x8*)(oa + kt * 32);
    f16x8 b8 = *(const f16x8*)(ob + kt * 32);
    f16x8 hv;
#pragma unroll
    for (int i = 0; i < 8; ++i)
      hv[i] = (f16)(((float)a8[i] + (float)b8[i]) * invl);
    *(f16x8*)(As + tid * 8) = hv;
    __syncthreads();

    f16x8 af[2], bf[4];
#pragma unroll
    for (int t = 0; t < 2; ++t)
      af[t] = *(const f16x8*)&As[(32 * wm + 16 * t + l16) * 32 + quad * 8];
#pragma unroll
    for (int t = 0; t < 4; ++t)
      bf[t] = *(const f16x8*)&Bs[(64 * wn + 16 * t + l16) * 32 + quad * 8];
#pragma unroll
    for (int i = 0; i < 2; ++i)
#pragma unroll
      for (int j = 0; j < 4; ++j)
        acc[i][j] = __builtin_amdgcn_mfma_f32_16x16x32_f16(af[i], bf[j], acc[i][j], 0, 0, 0);
  }

  const int cm = m0 + 32 * wm + 4 * quad;
  const int cn = n0 + 64 * wn + l16;
#pragma unroll
  for (int tn = 0; tn < 4; ++tn) {
    const float bv = bias3[cn + 16 * tn];
#pragma unroll
    for (int tm = 0; tm < 2; ++tm)
#pragma unroll
      for (int r = 0; r < 4; ++r)
        out[(size_t)(cm + 16 * tm + r) * 1024 + cn + 16 * tn] = acc[tm][tn][r] + bv;
  }
}

// ---------------------------------------------------------------------------
extern "C" void kernel_launch(void* const* d_in, const int* in_sizes, int n_in,
                              void* d_out, int out_size, void* d_ws, size_t ws_size,
                              hipStream_t stream) {
  const float* q  = (const float*)d_in[0];
  const float* k  = (const float*)d_in[1];
  const float* v  = (const float*)d_in[2];
  const int* mask = (const int*)d_in[3];
  const float* Wq = (const float*)d_in[4];
  const float* bq = (const float*)d_in[5];
  const float* Wk = (const float*)d_in[6];
  const float* bk = (const float*)d_in[7];
  const float* Wv = (const float*)d_in[8];
  const float* bv = (const float*)d_in[9];
  const float* Wo = (const float*)d_in[10];
  const float* bo = (const float*)d_in[11];
  float* out = (float*)d_out;

  // ws layout (bytes):
  //  0         xq (8 MB)  -> vhT after gemm_qkv
  //  8388608   xk (8 MB)  -> opart[0] after gemm_qkv
  //  16777216  xv (8 MB)  -> opart[1] after gemm_qkv
  //  25165824  Wt (8 MB)
  //  33554432  qh (8 MB)
  //  41943040  vh (8 MB)
  //  50331648  khc (8 MB)
  //  58720256  lpart (512 KB) | bias (16 KB) | idx (16 KB) | inv (16 KB) | nk
  char* ws = (char*)d_ws;
  f16* xqkv   = (f16*)(ws);
  f16* Wt     = (f16*)(ws + 25165824);
  f16* qh     = (f16*)(ws + 33554432);
  f16* vh     = (f16*)(ws + 41943040);
  f16* khc    = (f16*)(ws + 50331648);
  float* lpart = (float*)(ws + 58720256);
  float* bsw  = (float*)(ws + 59244544);
  int* idx    = (int*)(ws + 59260928);
  int* inv    = (int*)(ws + 59277312);
  int* nk     = (int*)(ws + 59293696);
  f16* vhT    = (f16*)(ws);             // aliases xq (dead after gemm_qkv)
  f16* opart  = (f16*)(ws + 8388608);   // aliases xk|xv (dead after gemm_qkv)

  dim3 blk(256);

  prep<<<dim3(7186), blk, 0, stream>>>(q, k, v, mask, Wq, Wk, Wv, Wo,
                                       bq, bk, bv, bo, xqkv, Wt, bsw,
                                       idx, inv, nk, khc);

  gemm_qkv<<<dim3(8, 32, 3), blk, 0, stream>>>(xqkv, Wt, bsw,
                                               qh, khc, vh, inv);

  vtrans<<<dim3(32, 32), blk, 0, stream>>>(vh, idx, nk, vhT);

  attn_mfma<<<dim3(16, 32, 2), blk, 0, stream>>>(qh, khc, vhT, nk,
                                                 opart, lpart);

  gemm_out<<<dim3(8, 64), blk, 0, stream>>>(opart, lpart, Wt + 3145728,
                                            bsw + 3072, out);
}